// Round 3
// baseline (602.193 us; speedup 1.0000x reference)
//
#include <hip/hip_runtime.h>
#include <hip/hip_bf16.h>

typedef unsigned int u32;

#define TILE 16
#define HALO 18           // TILE + 2
#define NPIX (HALO*HALO)  // 324

// ---- bf16 pack/unpack helpers ----
__device__ __forceinline__ float bf_lo(u32 v) { return __uint_as_float(v << 16); }
__device__ __forceinline__ float bf_hi(u32 v) { return __uint_as_float(v & 0xffff0000u); }
__device__ __forceinline__ u32 f2bf(float f) {
    u32 u = __float_as_uint(f);
    return (u + 0x7fffu + ((u >> 16) & 1u)) >> 16;   // RNE
}
__device__ __forceinline__ u32 pack2(float a, float b) { return f2bf(a) | (f2bf(b) << 16); }

// ---- dtype-generic loaders (input side only) ----
template<typename T> struct Ld;
template<> struct Ld<__hip_bfloat16> {
    static __device__ __forceinline__ float f(const __hip_bfloat16* p) { return (float)(*p); }
    static __device__ __forceinline__ u32 pair(const __hip_bfloat16* a, int pi) {
        return reinterpret_cast<const u32*>(a)[pi];
    }
};
template<> struct Ld<float> {
    static __device__ __forceinline__ float f(const float* p) { return *p; }
    static __device__ __forceinline__ u32 pair(const float* a, int pi) {
        return pack2(a[2*pi], a[2*pi+1]);
    }
};

// w_s packed-pair layout (u32 indices):
//   mw1 rows 0..22 [23][32] @0, mw2 [64][5] @736, mb2 @1056,
//   uw1 [20][32] @1061, ub1 @1701, uw2 [64][5] @1733,
//   ub2 @2053, gam @2058, bet @2063, total 2068
#define W_MW2 736
#define W_MB2 1056
#define W_UW1 1061
#define W_UB1 1701
#define W_UW2 1733
#define W_UB2 2053
#define W_GAM 2058
#define W_BET 2063
#define W_TOT 2068

template<typename T>
__device__ __forceinline__ void body(
    const T* __restrict__ beliefs, const T* __restrict__ cons, const T* __restrict__ fn,
    const T* __restrict__ mw1, const T* __restrict__ mb1, const T* __restrict__ mw2,
    const T* __restrict__ mb2, const T* __restrict__ uw1, const T* __restrict__ ub1,
    const T* __restrict__ uw2, const T* __restrict__ ub2, const T* __restrict__ gam,
    const T* __restrict__ bet, float* __restrict__ out,
    float* bel_s, u32* nbp_s, u32* w_s, float* fnb_s)
{
    const int tid = threadIdx.x;
    const int b  = blockIdx.z;
    const int y0 = blockIdx.y * TILE;
    const int x0 = blockIdx.x * TILE;

    // ---- stage all weights as packed bf16 pairs (8.3 KB) ----
    for (int i = tid; i < W_TOT; i += 256) {
        u32 v;
        if      (i < 736)  v = Ld<T>::pair(mw1, i);          // rows 0..22 of mw1
        else if (i < 1056) v = Ld<T>::pair(mw2, i - 736);
        else if (i < 1061) v = Ld<T>::pair(mb2, i - 1056);
        else if (i < 1701) v = Ld<T>::pair(uw1, i - 1061);
        else if (i < 1733) v = Ld<T>::pair(ub1, i - 1701);
        else if (i < 2053) v = Ld<T>::pair(uw2, i - 1733);
        else if (i < 2058) v = Ld<T>::pair(ub2, i - 2053);
        else if (i < 2063) v = Ld<T>::pair(gam, i - 2058);
        else               v = Ld<T>::pair(bet, i - 2063);
        w_s[i] = v;
    }

    // ---- filename bias: fnb[h] = mb1[h] + sum_f fn[b,f]*mw1[23+f][h] (fp32) ----
    if (tid < 64) {
        float acc = Ld<T>::f(mb1 + tid);
        #pragma unroll 8
        for (int f = 0; f < 32; f++)
            acc += Ld<T>::f(fn + b*32 + f) * Ld<T>::f(mw1 + (23 + f)*64 + tid);
        fnb_s[tid] = acc;
    }

    // ---- stage beliefs tile + replicate halo (fp32) ----
    for (int idx = tid; idx < NPIX*10; idx += 256) {
        int p  = idx / 10, c = idx - p*10;
        int py = p / HALO, px = p - py*HALO;
        int gy = y0 - 1 + py; gy = gy < 0 ? 0 : (gy > 127 ? 127 : gy);
        int gx = x0 - 1 + px; gx = gx < 0 ? 0 : (gx > 127 ? 127 : gx);
        bel_s[idx] = Ld<T>::f(beliefs + ((size_t)(b*128 + gy)*128 + gx)*10 + c);
    }
    __syncthreads();

    // ---- neighbor projection: nbp[h][p] = sum_c bel[p][c]*mw1[10+c][h], packed bf16 ----
    for (int p = tid; p < NPIX; p += 256) {
        float bl[10];
        #pragma unroll
        for (int c = 0; c < 10; c++) bl[c] = bel_s[p*10 + c];
        #pragma unroll 4
        for (int hp = 0; hp < 32; hp++) {
            float t0 = 0.f, t1 = 0.f;
            #pragma unroll
            for (int c = 0; c < 10; c++) {
                u32 wv = w_s[(10 + c)*32 + hp];
                t0 += bl[c] * bf_lo(wv);
                t1 += bl[c] * bf_hi(wv);
            }
            nbp_s[hp*NPIX + p] = pack2(t0, t1);
        }
    }
    __syncthreads();

    // ---- per-pixel fused message + update + LayerNorm ----
    const int tx = tid & 15, ty = tid >> 4;
    const int pc = (ty + 1)*HALO + (tx + 1);

    float bel[10];
    #pragma unroll
    for (int c = 0; c < 10; c++) bel[c] = bel_s[pc*10 + c];

    const size_t gpix = (size_t)(b*128 + (y0 + ty))*128 + (x0 + tx);

    float con[24];
    #pragma unroll
    for (int j = 0; j < 24; j++) con[j] = Ld<T>::f(cons + gpix*24 + j);

    float acc2[10];
    #pragma unroll
    for (int c = 0; c < 10; c++) acc2[c] = 0.f;

    #pragma unroll 2
    for (int hp = 0; hp < 32; hp++) {
        const int h0 = 2*hp, h1 = h0 + 1;
        float t0 = fnb_s[h0], t1 = fnb_s[h1];
        #pragma unroll
        for (int c = 0; c < 10; c++) {
            u32 wv = w_s[c*32 + hp];
            t0 += bel[c] * bf_lo(wv);
            t1 += bel[c] * bf_hi(wv);
        }
        const u32 wc0 = w_s[20*32 + hp], wc1 = w_s[21*32 + hp], wc2 = w_s[22*32 + hp];
        const u32* nbb = nbp_s + hp*NPIX + pc - 19;
        float s0 = 0.f, s1 = 0.f;
        #pragma unroll
        for (int k = 0; k < 8; k++) {
            // OFFSETS (-1,-1)(-1,0)(-1,1)(0,-1)(0,1)(1,-1)(1,0)(1,1) -> pc + dy*18+dx, biased -19
            const int doff[8] = { 0, 1, 2, 18, 20, 36, 37, 38 };
            u32 nv = nbb[doff[k]];
            float c0 = con[k*3], c1 = con[k*3+1], c2 = con[k*3+2];
            float v0 = t0 + bf_lo(nv) + c0*bf_lo(wc0) + c1*bf_lo(wc1) + c2*bf_lo(wc2);
            float v1 = t1 + bf_hi(nv) + c0*bf_hi(wc0) + c1*bf_hi(wc1) + c2*bf_hi(wc2);
            s0 += fmaxf(v0, 0.f);
            s1 += fmaxf(v1, 0.f);
        }
        #pragma unroll
        for (int cq = 0; cq < 5; cq++) {
            u32 a0 = w_s[W_MW2 + h0*5 + cq];
            u32 a1 = w_s[W_MW2 + h1*5 + cq];
            acc2[2*cq]   += s0*bf_lo(a0) + s1*bf_lo(a1);
            acc2[2*cq+1] += s0*bf_hi(a0) + s1*bf_hi(a1);
        }
    }

    float agg[10];
    #pragma unroll
    for (int cq = 0; cq < 5; cq++) {
        u32 bp = w_s[W_MB2 + cq];
        agg[2*cq]   = acc2[2*cq]  *0.125f + bf_lo(bp);
        agg[2*cq+1] = acc2[2*cq+1]*0.125f + bf_hi(bp);
    }

    float od[10];
    #pragma unroll
    for (int c = 0; c < 10; c++) od[c] = 0.f;
    #pragma unroll 2
    for (int hp = 0; hp < 32; hp++) {
        u32 ubp = w_s[W_UB1 + hp];
        float u0 = bf_lo(ubp), u1 = bf_hi(ubp);
        #pragma unroll
        for (int c = 0; c < 10; c++) {
            u32 wv = w_s[W_UW1 + c*32 + hp];
            u0 += bel[c] * bf_lo(wv);
            u1 += bel[c] * bf_hi(wv);
        }
        #pragma unroll
        for (int c = 0; c < 10; c++) {
            u32 wv = w_s[W_UW1 + (10 + c)*32 + hp];
            u0 += agg[c] * bf_lo(wv);
            u1 += agg[c] * bf_hi(wv);
        }
        u0 = fmaxf(u0, 0.f); u1 = fmaxf(u1, 0.f);
        const int h0 = 2*hp, h1 = h0 + 1;
        #pragma unroll
        for (int cq = 0; cq < 5; cq++) {
            u32 a0 = w_s[W_UW2 + h0*5 + cq];
            u32 a1 = w_s[W_UW2 + h1*5 + cq];
            od[2*cq]   += u0*bf_lo(a0) + u1*bf_lo(a1);
            od[2*cq+1] += u0*bf_hi(a0) + u1*bf_hi(a1);
        }
    }

    float x[10], mu = 0.f;
    #pragma unroll
    for (int cq = 0; cq < 5; cq++) {
        u32 bp = w_s[W_UB2 + cq];
        x[2*cq]   = bel[2*cq]   + 0.5f*(od[2*cq]   + bf_lo(bp));
        x[2*cq+1] = bel[2*cq+1] + 0.5f*(od[2*cq+1] + bf_hi(bp));
        mu += x[2*cq] + x[2*cq+1];
    }
    mu *= 0.1f;
    float var = 0.f;
    #pragma unroll
    for (int c = 0; c < 10; c++) { float d = x[c] - mu; var += d*d; }
    var *= 0.1f;
    const float rs = rsqrtf(var + 1e-5f);

    // ---- fp32 output: 10 floats per pixel, 5x float2 stores (8B aligned) ----
    float2* op = reinterpret_cast<float2*>(out + gpix*10);
    #pragma unroll
    for (int q = 0; q < 5; q++) {
        u32 gp = w_s[W_GAM + q], bq = w_s[W_BET + q];
        float2 r;
        r.x = (x[2*q]   - mu)*rs*bf_lo(gp) + bf_lo(bq);
        r.y = (x[2*q+1] - mu)*rs*bf_hi(gp) + bf_hi(bq);
        op[q] = r;
    }
}

__global__ __launch_bounds__(256) void cmp_fused_kernel(
    const void* beliefs, const void* cons, const void* fn,
    const void* mw1, const void* mb1, const void* mw2, const void* mb2,
    const void* uw1, const void* ub1, const void* uw2, const void* ub2,
    const void* gam, const void* bet, float* out)
{
    __shared__ float bel_s[NPIX*10];   // 12.96 KB
    __shared__ u32   nbp_s[32*NPIX];   // 41.47 KB
    __shared__ u32   w_s[W_TOT];       // 8.27 KB
    __shared__ float fnb_s[64];        // 0.26 KB  -> 62.96 KB total

    // ---- dtype sniff: constraints ~ U[0,1). bf16 => bit15 (sign of elem 2i+1) always 0.
    // fp32 => bit15 is a random mantissa bit => set w.p. 1-2^-32 over 32 words.
    u32 acc = 0;
    const u32* cw = (const u32*)cons;
    #pragma unroll
    for (int i = 0; i < 32; i++) acc |= cw[i];

    if (acc & 0x8000u) {
        body<float>((const float*)beliefs, (const float*)cons, (const float*)fn,
                    (const float*)mw1, (const float*)mb1, (const float*)mw2, (const float*)mb2,
                    (const float*)uw1, (const float*)ub1, (const float*)uw2, (const float*)ub2,
                    (const float*)gam, (const float*)bet, out, bel_s, nbp_s, w_s, fnb_s);
    } else {
        body<__hip_bfloat16>((const __hip_bfloat16*)beliefs, (const __hip_bfloat16*)cons,
                    (const __hip_bfloat16*)fn,
                    (const __hip_bfloat16*)mw1, (const __hip_bfloat16*)mb1,
                    (const __hip_bfloat16*)mw2, (const __hip_bfloat16*)mb2,
                    (const __hip_bfloat16*)uw1, (const __hip_bfloat16*)ub1,
                    (const __hip_bfloat16*)uw2, (const __hip_bfloat16*)ub2,
                    (const __hip_bfloat16*)gam, (const __hip_bfloat16*)bet,
                    out, bel_s, nbp_s, w_s, fnb_s);
    }
}

extern "C" void kernel_launch(void* const* d_in, const int* in_sizes, int n_in,
                              void* d_out, int out_size, void* d_ws, size_t ws_size,
                              hipStream_t stream) {
    (void)in_sizes; (void)n_in; (void)out_size; (void)d_ws; (void)ws_size;
    cmp_fused_kernel<<<dim3(8, 8, 64), dim3(256), 0, stream>>>(
        d_in[0], d_in[1], d_in[2], d_in[3], d_in[4], d_in[5], d_in[6],
        d_in[7], d_in[8], d_in[9], d_in[10], d_in[11], d_in[12], (float*)d_out);
}

// Round 4
// 320.180 us; speedup vs baseline: 1.8808x; 1.8808x over previous
//
#include <hip/hip_runtime.h>
#include <hip/hip_bf16.h>

typedef unsigned int u32;
typedef _Float16 h2 __attribute__((ext_vector_type(2)));

#define TILE 16
#define HALO 18           // TILE + 2
#define NPIX (HALO*HALO)  // 324

// ================= ws layout (dword units) =================
// FNBP  [64][32] h2 pairs @ 0      : fnb[b][h-pair] = mb1 + fn@mw1[23:55]
// Weight pairs (h2) base  @ 2048:
#define W_SELF   0        // [10][32]  (mw1[c][2hp], mw1[c][2hp+1])
#define W_NBW    320      // [5][64]   (mw1[10+2q][h], mw1[11+2q][h])  c-pairs
#define W_WC     640      // [3][32]   (mw1[20+r][2hp], mw1[20+r][2hp+1])
#define W_MW2    736      // [10][32]  (mw2[2hp][c], mw2[2hp+1][c])
#define W_UB1    1056     // [32]      (ub1[2hp], ub1[2hp+1])
#define W_UW1    1088     // [20][32]  (uw1[c][2hp], uw1[c][2hp+1])
#define W_UW2    1728     // [10][32]  (uw2[2hp][c], uw2[2hp+1][c])
#define WS_W     2048
#define WS_SCAL  4096     // f32: mb2[0:10] ub2[10:20] gam[20:30] bet[30:40]
#define WS_DWORDS 4136    // 16544 bytes needed

// ---------------- helpers ----------------
__device__ __forceinline__ h2 pkrtz(float a, float b) {
    return __builtin_bit_cast(h2, __builtin_amdgcn_cvt_pkrtz(a, b));
}
__device__ __forceinline__ float dot2f(h2 a, h2 b, float c) {
#if __has_builtin(__builtin_amdgcn_fdot2)
    return __builtin_amdgcn_fdot2(__builtin_bit_cast(__attribute__((ext_vector_type(2))) __fp16, a),
                                  __builtin_bit_cast(__attribute__((ext_vector_type(2))) __fp16, b),
                                  c, false);
#else
    return c + (float)a.x * (float)b.x + (float)a.y * (float)b.y;
#endif
}
__device__ __forceinline__ h2 relu2(h2 v) {
    h2 z = (h2)(_Float16)0;
#if __has_builtin(__builtin_elementwise_max)
    return __builtin_elementwise_max(v, z);
#else
    h2 r;
    r.x = v.x > (_Float16)0 ? v.x : (_Float16)0;
    r.y = v.y > (_Float16)0 ? v.y : (_Float16)0;
    return r;
#endif
}

// ---------- prep: fnb per batch + f16-pair weight repack into ws ----------
__global__ __launch_bounds__(64) void prep_kernel(
    const float* __restrict__ fn,  const float* __restrict__ mw1, const float* __restrict__ mb1,
    const float* __restrict__ mw2, const float* __restrict__ mb2, const float* __restrict__ uw1,
    const float* __restrict__ ub1, const float* __restrict__ uw2, const float* __restrict__ ub2,
    const float* __restrict__ gam, const float* __restrict__ bet, u32* __restrict__ ws)
{
    const int b = blockIdx.x, t = threadIdx.x;
    h2* wh = (h2*)ws;
    if (t < 32) {
        float a0 = mb1[2*t], a1 = mb1[2*t+1];
        for (int f = 0; f < 32; f++) {
            float fv = fn[b*32 + f];
            a0 += fv * mw1[(23+f)*64 + 2*t];
            a1 += fv * mw1[(23+f)*64 + 2*t+1];
        }
        wh[b*32 + t] = pkrtz(a0, a1);
    }
    if (b == 0) {
        for (int i = t; i < 2048; i += 64) {
            float a, c; int j;
            if      (i < 320)  { int cc = i>>5,  hp = i&31;  a = mw1[cc*64 + 2*hp];       c = mw1[cc*64 + 2*hp+1]; }
            else if (i < 640)  { j = i-320;  int q = j>>6, hh = j&63; a = mw1[(10+2*q)*64 + hh]; c = mw1[(11+2*q)*64 + hh]; }
            else if (i < 736)  { j = i-640;  int r = j>>5, hp = j&31; a = mw1[(20+r)*64 + 2*hp]; c = mw1[(20+r)*64 + 2*hp+1]; }
            else if (i < 1056) { j = i-736;  int cc = j>>5, hp = j&31; a = mw2[(2*hp)*10 + cc];  c = mw2[(2*hp+1)*10 + cc]; }
            else if (i < 1088) { j = i-1056; a = ub1[2*j]; c = ub1[2*j+1]; }
            else if (i < 1728) { j = i-1088; int cc = j>>5, hp = j&31; a = uw1[cc*64 + 2*hp];    c = uw1[cc*64 + 2*hp+1]; }
            else               { j = i-1728; int cc = j>>5, hp = j&31; a = uw2[(2*hp)*10 + cc];  c = uw2[(2*hp+1)*10 + cc]; }
            wh[WS_W + i] = pkrtz(a, c);
        }
        if (t < 40) {
            float v;
            if      (t < 10) v = mb2[t];
            else if (t < 20) v = ub2[t-10];
            else if (t < 30) v = gam[t-20];
            else             v = bet[t-30];
            ((float*)ws)[WS_SCAL + t] = v;
        }
    }
}

// ---------- main fused kernel (f16-pair math, SGPR weights) ----------
__global__ __launch_bounds__(256, 3) void mp_kernel(
    const float* __restrict__ beliefs, const float* __restrict__ cons,
    const u32* __restrict__ ws, float* __restrict__ out)
{
    __shared__ h2 bel_s[NPIX*5];    // 6.48 KB, [pixel][c-pair]
    __shared__ h2 nbp_s[32*NPIX];   // 41.47 KB, [hpair][pixel]

    const int tid = threadIdx.x;
    const int b = blockIdx.z, y0 = blockIdx.y*TILE, x0 = blockIdx.x*TILE;

    const h2* Wfnb = (const h2*)ws;               // [64][32]
    const h2* W    = ((const h2*)ws) + WS_W;
    const float* SC = ((const float*)ws) + WS_SCAL;

    // ---- stage beliefs c-pairs with replicate halo ----
    for (int i = tid; i < NPIX*5; i += 256) {
        int p = i/5, q = i - p*5;
        int py = p/HALO, px = p - py*HALO;
        int gy = y0-1+py; gy = gy<0?0:(gy>127?127:gy);
        int gx = x0-1+px; gx = gx<0?0:(gx>127?127:gx);
        const float2 v = *(const float2*)(beliefs + (size_t)((b*128+gy)*128+gx)*10 + 2*q);
        bel_s[i] = pkrtz(v.x, v.y);
    }
    __syncthreads();

    // ---- nbp[hpair][p] = bel[p] @ mw1[10:20], dot2 over c-pairs, fp32 accum ----
    for (int p = tid; p < NPIX; p += 256) {
        h2 bc[5];
        #pragma unroll
        for (int q = 0; q < 5; q++) bc[q] = bel_s[p*5 + q];
        #pragma unroll 4
        for (int hp = 0; hp < 32; hp++) {
            float a0 = 0.f, a1 = 0.f;
            #pragma unroll
            for (int q = 0; q < 5; q++) {
                a0 = dot2f(bc[q], W[W_NBW + q*64 + 2*hp],     a0);
                a1 = dot2f(bc[q], W[W_NBW + q*64 + 2*hp + 1], a1);
            }
            nbp_s[hp*NPIX + p] = pkrtz(a0, a1);
        }
    }
    __syncthreads();

    // ---- per-pixel fused compute ----
    const int tx = tid & 15, ty = tid >> 4;
    const int pc = (ty+1)*HALO + (tx+1);
    const size_t gpix = (size_t)((b*128 + (y0+ty))*128 + (x0+tx));

    float bel[10]; h2 beld[10];
    {
        const float2* bp = (const float2*)(beliefs + gpix*10);
        #pragma unroll
        for (int q = 0; q < 5; q++) {
            float2 v = bp[q];
            bel[2*q] = v.x; bel[2*q+1] = v.y;
            beld[2*q]   = pkrtz(v.x, v.x);
            beld[2*q+1] = pkrtz(v.y, v.y);
        }
    }
    h2 cond[24];
    {
        const float4* cp = (const float4*)(cons + gpix*24);
        #pragma unroll
        for (int r = 0; r < 6; r++) {
            float4 v = cp[r];
            cond[4*r+0] = pkrtz(v.x, v.x);
            cond[4*r+1] = pkrtz(v.y, v.y);
            cond[4*r+2] = pkrtz(v.z, v.z);
            cond[4*r+3] = pkrtz(v.w, v.w);
        }
    }

    float acc2[10];
    #pragma unroll
    for (int c = 0; c < 10; c++) acc2[c] = 0.f;

    #pragma unroll 4
    for (int hp = 0; hp < 32; hp++) {
        h2 t01 = Wfnb[b*32 + hp];
        #pragma unroll
        for (int c = 0; c < 10; c++) t01 = beld[c]*W[W_SELF + c*32 + hp] + t01;
        const h2 wc0 = W[W_WC + hp], wc1 = W[W_WC + 32 + hp], wc2 = W[W_WC + 64 + hp];
        const h2* nbb = nbp_s + hp*NPIX + pc - 19;
        h2 s01 = (h2)(_Float16)0;
        #pragma unroll
        for (int k = 0; k < 8; k++) {
            // OFFSETS (-1,-1)(-1,0)(-1,1)(0,-1)(0,1)(1,-1)(1,0)(1,1) -> pc+dy*18+dx, biased -19
            const int doff[8] = {0,1,2,18,20,36,37,38};
            h2 v = t01 + nbb[doff[k]];
            v = cond[k*3+0]*wc0 + v;
            v = cond[k*3+1]*wc1 + v;
            v = cond[k*3+2]*wc2 + v;
            s01 += relu2(v);
        }
        #pragma unroll
        for (int c = 0; c < 10; c++) acc2[c] = dot2f(s01, W[W_MW2 + c*32 + hp], acc2[c]);
    }

    // agg = mean + mb2, duplicated-f16
    h2 aggd[10];
    #pragma unroll
    for (int c = 0; c < 10; c++) {
        float a = acc2[c]*0.125f + SC[c];
        aggd[c] = pkrtz(a, a);
    }

    float od[10];
    #pragma unroll
    for (int c = 0; c < 10; c++) od[c] = 0.f;

    #pragma unroll 4
    for (int hp = 0; hp < 32; hp++) {
        h2 u01 = W[W_UB1 + hp];
        #pragma unroll
        for (int c = 0; c < 10; c++) u01 = beld[c]*W[W_UW1 + c*32 + hp] + u01;
        #pragma unroll
        for (int c = 0; c < 10; c++) u01 = aggd[c]*W[W_UW1 + (10+c)*32 + hp] + u01;
        u01 = relu2(u01);
        #pragma unroll
        for (int c = 0; c < 10; c++) od[c] = dot2f(u01, W[W_UW2 + c*32 + hp], od[c]);
    }

    float x[10], mu = 0.f;
    #pragma unroll
    for (int c = 0; c < 10; c++) { x[c] = bel[c] + 0.5f*(od[c] + SC[10+c]); mu += x[c]; }
    mu *= 0.1f;
    float var = 0.f;
    #pragma unroll
    for (int c = 0; c < 10; c++) { float d = x[c] - mu; var += d*d; }
    var *= 0.1f;
    const float rs = rsqrtf(var + 1e-5f);

    float2* op = (float2*)(out + gpix*10);
    #pragma unroll
    for (int q = 0; q < 5; q++) {
        float2 r;
        r.x = (x[2*q]   - mu)*rs*SC[20+2*q]   + SC[30+2*q];
        r.y = (x[2*q+1] - mu)*rs*SC[20+2*q+1] + SC[30+2*q+1];
        op[q] = r;
    }
}

// ================== fallback (round-3 proven kernel, fp32 inputs) ==================
__device__ __forceinline__ float bf_lo(u32 v) { return __uint_as_float(v << 16); }
__device__ __forceinline__ float bf_hi(u32 v) { return __uint_as_float(v & 0xffff0000u); }
__device__ __forceinline__ u32 f2bf(float f) {
    u32 u = __float_as_uint(f);
    return (u + 0x7fffu + ((u >> 16) & 1u)) >> 16;
}
__device__ __forceinline__ u32 pack2(float a, float b) { return f2bf(a) | (f2bf(b) << 16); }
__device__ __forceinline__ u32 fpair(const float* a, int pi) { return pack2(a[2*pi], a[2*pi+1]); }

#define FW_MW2 736
#define FW_MB2 1056
#define FW_UW1 1061
#define FW_UB1 1701
#define FW_UW2 1733
#define FW_UB2 2053
#define FW_GAM 2058
#define FW_BET 2063
#define FW_TOT 2068

__global__ __launch_bounds__(256) void fallback_kernel(
    const float* __restrict__ beliefs, const float* __restrict__ cons, const float* __restrict__ fn,
    const float* __restrict__ mw1, const float* __restrict__ mb1, const float* __restrict__ mw2,
    const float* __restrict__ mb2, const float* __restrict__ uw1, const float* __restrict__ ub1,
    const float* __restrict__ uw2, const float* __restrict__ ub2, const float* __restrict__ gam,
    const float* __restrict__ bet, float* __restrict__ out)
{
    __shared__ float bel_s[NPIX*10];
    __shared__ u32   nbp_s[32*NPIX];
    __shared__ u32   w_s[FW_TOT];
    __shared__ float fnb_s[64];

    const int tid = threadIdx.x;
    const int b  = blockIdx.z;
    const int y0 = blockIdx.y * TILE;
    const int x0 = blockIdx.x * TILE;

    for (int i = tid; i < FW_TOT; i += 256) {
        u32 v;
        if      (i < 736)  v = fpair(mw1, i);
        else if (i < 1056) v = fpair(mw2, i - 736);
        else if (i < 1061) v = fpair(mb2, i - 1056);
        else if (i < 1701) v = fpair(uw1, i - 1061);
        else if (i < 1733) v = fpair(ub1, i - 1701);
        else if (i < 2053) v = fpair(uw2, i - 1733);
        else if (i < 2058) v = fpair(ub2, i - 2053);
        else if (i < 2063) v = fpair(gam, i - 2058);
        else               v = fpair(bet, i - 2063);
        w_s[i] = v;
    }
    if (tid < 64) {
        float acc = mb1[tid];
        #pragma unroll 8
        for (int f = 0; f < 32; f++)
            acc += fn[b*32 + f] * mw1[(23 + f)*64 + tid];
        fnb_s[tid] = acc;
    }
    for (int idx = tid; idx < NPIX*10; idx += 256) {
        int p = idx/10, c = idx - p*10;
        int py = p/HALO, px = p - py*HALO;
        int gy = y0-1+py; gy = gy<0?0:(gy>127?127:gy);
        int gx = x0-1+px; gx = gx<0?0:(gx>127?127:gx);
        bel_s[idx] = beliefs[((size_t)(b*128+gy)*128+gx)*10 + c];
    }
    __syncthreads();

    for (int p = tid; p < NPIX; p += 256) {
        float bl[10];
        #pragma unroll
        for (int c = 0; c < 10; c++) bl[c] = bel_s[p*10 + c];
        #pragma unroll 4
        for (int hp = 0; hp < 32; hp++) {
            float t0 = 0.f, t1 = 0.f;
            #pragma unroll
            for (int c = 0; c < 10; c++) {
                u32 wv = w_s[(10 + c)*32 + hp];
                t0 += bl[c] * bf_lo(wv);
                t1 += bl[c] * bf_hi(wv);
            }
            nbp_s[hp*NPIX + p] = pack2(t0, t1);
        }
    }
    __syncthreads();

    const int tx = tid & 15, ty = tid >> 4;
    const int pc = (ty + 1)*HALO + (tx + 1);
    float bel[10];
    #pragma unroll
    for (int c = 0; c < 10; c++) bel[c] = bel_s[pc*10 + c];
    const size_t gpix = (size_t)(b*128 + (y0 + ty))*128 + (x0 + tx);
    float con[24];
    #pragma unroll
    for (int j = 0; j < 24; j++) con[j] = cons[gpix*24 + j];

    float acc2[10];
    #pragma unroll
    for (int c = 0; c < 10; c++) acc2[c] = 0.f;

    #pragma unroll 2
    for (int hp = 0; hp < 32; hp++) {
        const int h0 = 2*hp, h1 = h0 + 1;
        float t0 = fnb_s[h0], t1 = fnb_s[h1];
        #pragma unroll
        for (int c = 0; c < 10; c++) {
            u32 wv = w_s[c*32 + hp];
            t0 += bel[c] * bf_lo(wv);
            t1 += bel[c] * bf_hi(wv);
        }
        const u32 wc0 = w_s[20*32 + hp], wc1 = w_s[21*32 + hp], wc2 = w_s[22*32 + hp];
        const u32* nbb = nbp_s + hp*NPIX + pc - 19;
        float s0 = 0.f, s1 = 0.f;
        #pragma unroll
        for (int k = 0; k < 8; k++) {
            const int doff[8] = { 0, 1, 2, 18, 20, 36, 37, 38 };
            u32 nv = nbb[doff[k]];
            float c0 = con[k*3], c1 = con[k*3+1], c2 = con[k*3+2];
            float v0 = t0 + bf_lo(nv) + c0*bf_lo(wc0) + c1*bf_lo(wc1) + c2*bf_lo(wc2);
            float v1 = t1 + bf_hi(nv) + c0*bf_hi(wc0) + c1*bf_hi(wc1) + c2*bf_hi(wc2);
            s0 += fmaxf(v0, 0.f);
            s1 += fmaxf(v1, 0.f);
        }
        #pragma unroll
        for (int cq = 0; cq < 5; cq++) {
            u32 a0 = w_s[FW_MW2 + h0*5 + cq];
            u32 a1 = w_s[FW_MW2 + h1*5 + cq];
            acc2[2*cq]   += s0*bf_lo(a0) + s1*bf_lo(a1);
            acc2[2*cq+1] += s0*bf_hi(a0) + s1*bf_hi(a1);
        }
    }

    float agg[10];
    #pragma unroll
    for (int cq = 0; cq < 5; cq++) {
        u32 bp = w_s[FW_MB2 + cq];
        agg[2*cq]   = acc2[2*cq]  *0.125f + bf_lo(bp);
        agg[2*cq+1] = acc2[2*cq+1]*0.125f + bf_hi(bp);
    }

    float od[10];
    #pragma unroll
    for (int c = 0; c < 10; c++) od[c] = 0.f;
    #pragma unroll 2
    for (int hp = 0; hp < 32; hp++) {
        u32 ubp = w_s[FW_UB1 + hp];
        float u0 = bf_lo(ubp), u1 = bf_hi(ubp);
        #pragma unroll
        for (int c = 0; c < 10; c++) {
            u32 wv = w_s[FW_UW1 + c*32 + hp];
            u0 += bel[c] * bf_lo(wv);
            u1 += bel[c] * bf_hi(wv);
        }
        #pragma unroll
        for (int c = 0; c < 10; c++) {
            u32 wv = w_s[FW_UW1 + (10 + c)*32 + hp];
            u0 += agg[c] * bf_lo(wv);
            u1 += agg[c] * bf_hi(wv);
        }
        u0 = fmaxf(u0, 0.f); u1 = fmaxf(u1, 0.f);
        const int h0 = 2*hp, h1 = h0 + 1;
        #pragma unroll
        for (int cq = 0; cq < 5; cq++) {
            u32 a0 = w_s[FW_UW2 + h0*5 + cq];
            u32 a1 = w_s[FW_UW2 + h1*5 + cq];
            od[2*cq]   += u0*bf_lo(a0) + u1*bf_lo(a1);
            od[2*cq+1] += u0*bf_hi(a0) + u1*bf_hi(a1);
        }
    }

    float x[10], mu = 0.f;
    #pragma unroll
    for (int cq = 0; cq < 5; cq++) {
        u32 bp = w_s[FW_UB2 + cq];
        x[2*cq]   = bel[2*cq]   + 0.5f*(od[2*cq]   + bf_lo(bp));
        x[2*cq+1] = bel[2*cq+1] + 0.5f*(od[2*cq+1] + bf_hi(bp));
        mu += x[2*cq] + x[2*cq+1];
    }
    mu *= 0.1f;
    float var = 0.f;
    #pragma unroll
    for (int c = 0; c < 10; c++) { float d = x[c] - mu; var += d*d; }
    var *= 0.1f;
    const float rs = rsqrtf(var + 1e-5f);

    float2* op = reinterpret_cast<float2*>(out + gpix*10);
    #pragma unroll
    for (int q = 0; q < 5; q++) {
        u32 gp = w_s[FW_GAM + q], bq = w_s[FW_BET + q];
        float2 r;
        r.x = (x[2*q]   - mu)*rs*bf_lo(gp) + bf_lo(bq);
        r.y = (x[2*q+1] - mu)*rs*bf_hi(gp) + bf_hi(bq);
        op[q] = r;
    }
}

extern "C" void kernel_launch(void* const* d_in, const int* in_sizes, int n_in,
                              void* d_out, int out_size, void* d_ws, size_t ws_size,
                              hipStream_t stream) {
    (void)in_sizes; (void)n_in; (void)out_size;
    const float* beliefs = (const float*)d_in[0];
    const float* cons    = (const float*)d_in[1];
    const float* fn      = (const float*)d_in[2];
    const float* mw1     = (const float*)d_in[3];
    const float* mb1     = (const float*)d_in[4];
    const float* mw2     = (const float*)d_in[5];
    const float* mb2     = (const float*)d_in[6];
    const float* uw1     = (const float*)d_in[7];
    const float* ub1     = (const float*)d_in[8];
    const float* uw2     = (const float*)d_in[9];
    const float* ub2     = (const float*)d_in[10];
    const float* gam     = (const float*)d_in[11];
    const float* bet     = (const float*)d_in[12];
    float* outp = (float*)d_out;

    if (ws_size >= (size_t)WS_DWORDS*4) {
        prep_kernel<<<dim3(64), dim3(64), 0, stream>>>(
            fn, mw1, mb1, mw2, mb2, uw1, ub1, uw2, ub2, gam, bet, (u32*)d_ws);
        mp_kernel<<<dim3(8, 8, 64), dim3(256), 0, stream>>>(
            beliefs, cons, (const u32*)d_ws, outp);
    } else {
        fallback_kernel<<<dim3(8, 8, 64), dim3(256), 0, stream>>>(
            beliefs, cons, fn, mw1, mb1, mw2, mb2, uw1, ub1, uw2, ub2, gam, bet, outp);
    }
}

// Round 6
// 318.317 us; speedup vs baseline: 1.8918x; 1.0059x over previous
//
#include <hip/hip_runtime.h>
#include <hip/hip_bf16.h>

typedef unsigned int u32;
typedef _Float16 h2 __attribute__((ext_vector_type(2)));

#define TILE 16
#define HALO 18           // TILE + 2
#define NPIX (HALO*HALO)  // 324
#define NBSTRIDE 36       // dwords per pixel row in nbp (32 used + 4 pad, 144B = 16B-aligned)

// ================= ws layout (dword units) =================
// FNBP  [64][32] h2 pairs @ 0      : fnb[b][h-pair] = mb1 + fn@mw1[23:55]
// Weight pairs (h2) base  @ 2048:
#define W_SELF   0        // [10][32]  (mw1[c][2hp], mw1[c][2hp+1])
#define W_NBW    320      // [5][64]   (mw1[10+2q][h], mw1[11+2q][h])  c-pairs
#define W_WC     640      // [3][32]   (mw1[20+r][2hp], mw1[20+r][2hp+1])
#define W_MW2    736      // [10][32]  (mw2[2hp][c], mw2[2hp+1][c])
#define W_UB1    1056     // [32]      (ub1[2hp], ub1[2hp+1])
#define W_UW1    1088     // [20][32]  (uw1[c][2hp], uw1[c][2hp+1])
#define W_UW2    1728     // [10][32]  (uw2[2hp][c], uw2[2hp+1][c])
#define WS_W     2048
#define WS_SCAL  4096     // f32: mb2[0:10] ub2[10:20] gam[20:30] bet[30:40]
#define WS_DWORDS 4136    // 16544 bytes needed

// ---------------- helpers ----------------
__device__ __forceinline__ h2 pkrtz(float a, float b) {
    return __builtin_bit_cast(h2, __builtin_amdgcn_cvt_pkrtz(a, b));
}
#if __has_builtin(__builtin_elementwise_fma)
__device__ __forceinline__ h2 pkfma(h2 a, h2 b, h2 c) { return __builtin_elementwise_fma(a, b, c); }
#else
extern "C" __device__ h2 __ocml_fma_2f16(h2, h2, h2);
__device__ __forceinline__ h2 pkfma(h2 a, h2 b, h2 c) { return __ocml_fma_2f16(a, b, c); }
#endif
__device__ __forceinline__ float dot2f(h2 a, h2 b, float c) {
#if __has_builtin(__builtin_amdgcn_fdot2)
    return __builtin_amdgcn_fdot2(__builtin_bit_cast(__attribute__((ext_vector_type(2))) __fp16, a),
                                  __builtin_bit_cast(__attribute__((ext_vector_type(2))) __fp16, b),
                                  c, false);
#else
    return fmaf((float)a.x, (float)b.x, fmaf((float)a.y, (float)b.y, c));  // 2x v_fma_mix_f32
#endif
}
__device__ __forceinline__ h2 relu2(h2 v) {
    h2 z = (h2)(_Float16)0;
#if __has_builtin(__builtin_elementwise_max)
    return __builtin_elementwise_max(v, z);
#else
    h2 r;
    r.x = v.x > (_Float16)0 ? v.x : (_Float16)0;
    r.y = v.y > (_Float16)0 ? v.y : (_Float16)0;
    return r;
#endif
}
__device__ __forceinline__ h2 h2cast(u32 v) { return __builtin_bit_cast(h2, v); }

// ---------- prep: fnb per batch + f16-pair weight repack into ws ----------
__global__ __launch_bounds__(64) void prep_kernel(
    const float* __restrict__ fn,  const float* __restrict__ mw1, const float* __restrict__ mb1,
    const float* __restrict__ mw2, const float* __restrict__ mb2, const float* __restrict__ uw1,
    const float* __restrict__ ub1, const float* __restrict__ uw2, const float* __restrict__ ub2,
    const float* __restrict__ gam, const float* __restrict__ bet, u32* __restrict__ ws)
{
    const int b = blockIdx.x, t = threadIdx.x;
    h2* wh = (h2*)ws;
    if (t < 32) {
        float a0 = mb1[2*t], a1 = mb1[2*t+1];
        for (int f = 0; f < 32; f++) {
            float fv = fn[b*32 + f];
            a0 += fv * mw1[(23+f)*64 + 2*t];
            a1 += fv * mw1[(23+f)*64 + 2*t+1];
        }
        wh[b*32 + t] = pkrtz(a0, a1);
    }
    if (b == 0) {
        for (int i = t; i < 2048; i += 64) {
            float a, c; int j;
            if      (i < 320)  { int cc = i>>5,  hp = i&31;  a = mw1[cc*64 + 2*hp];       c = mw1[cc*64 + 2*hp+1]; }
            else if (i < 640)  { j = i-320;  int q = j>>6, hh = j&63; a = mw1[(10+2*q)*64 + hh]; c = mw1[(11+2*q)*64 + hh]; }
            else if (i < 736)  { j = i-640;  int r = j>>5, hp = j&31; a = mw1[(20+r)*64 + 2*hp]; c = mw1[(20+r)*64 + 2*hp+1]; }
            else if (i < 1056) { j = i-736;  int cc = j>>5, hp = j&31; a = mw2[(2*hp)*10 + cc];  c = mw2[(2*hp+1)*10 + cc]; }
            else if (i < 1088) { j = i-1056; a = ub1[2*j]; c = ub1[2*j+1]; }
            else if (i < 1728) { j = i-1088; int cc = j>>5, hp = j&31; a = uw1[cc*64 + 2*hp];    c = uw1[cc*64 + 2*hp+1]; }
            else               { j = i-1728; int cc = j>>5, hp = j&31; a = uw2[(2*hp)*10 + cc];  c = uw2[(2*hp+1)*10 + cc]; }
            wh[WS_W + i] = pkrtz(a, c);
        }
        if (t < 40) {
            float v;
            if      (t < 10) v = mb2[t];
            else if (t < 20) v = ub2[t-10];
            else if (t < 30) v = gam[t-20];
            else             v = bet[t-30];
            ((float*)ws)[WS_SCAL + t] = v;
        }
    }
}

// ---------- main fused kernel ----------
__global__ __launch_bounds__(256, 3) void mp_kernel(
    const float* __restrict__ beliefs, const float* __restrict__ cons,
    const u32* __restrict__ ws, float* __restrict__ out)
{
    __shared__ h2 bel_s[NPIX*5];                       // 6.48 KB, [pixel][c-pair]
    __shared__ __align__(16) u32 nbp_u[NPIX*NBSTRIDE]; // 46.66 KB, [pixel][hp] padded

    const int tid = threadIdx.x;
    const int b = blockIdx.z, y0 = blockIdx.y*TILE, x0 = blockIdx.x*TILE;

    const h2* Wfnb = (const h2*)ws;               // [64][32]
    const h2* W    = ((const h2*)ws) + WS_W;
    const float* SC = ((const float*)ws) + WS_SCAL;

    // ---- stage beliefs c-pairs with replicate halo ----
    for (int i = tid; i < NPIX*5; i += 256) {
        int p = i/5, q = i - p*5;
        int py = p/HALO, px = p - py*HALO;
        int gy = y0-1+py; gy = gy<0?0:(gy>127?127:gy);
        int gx = x0-1+px; gx = gx<0?0:(gx>127?127:gx);
        const float2 v = *(const float2*)(beliefs + (size_t)((b*128+gy)*128+gx)*10 + 2*q);
        bel_s[i] = pkrtz(v.x, v.y);
    }
    __syncthreads();

    // ---- nbp[p][hp] = bel[p] @ mw1[10:20] (dot2 over c-pairs, fp32 accum) ----
    for (int p = tid; p < NPIX; p += 256) {
        h2 bc[5];
        #pragma unroll
        for (int q = 0; q < 5; q++) bc[q] = bel_s[p*5 + q];
        #pragma unroll 4
        for (int hp = 0; hp < 32; hp++) {
            float a0 = 0.f, a1 = 0.f;
            #pragma unroll
            for (int q = 0; q < 5; q++) {
                a0 = dot2f(bc[q], W[W_NBW + q*64 + 2*hp],     a0);
                a1 = dot2f(bc[q], W[W_NBW + q*64 + 2*hp + 1], a1);
            }
            nbp_u[p*NBSTRIDE + hp] = __builtin_bit_cast(u32, pkrtz(a0, a1));
        }
    }
    __syncthreads();

    // ---- per-pixel fused compute ----
    const int tx = tid & 15, ty = tid >> 4;
    const int pc = (ty+1)*HALO + (tx+1);
    const size_t gpix = (size_t)((b*128 + (y0+ty))*128 + (x0+tx));

    // neighbor row bases: OFFSETS (-1,-1)(-1,0)(-1,1)(0,-1)(0,1)(1,-1)(1,0)(1,1)
    int p36[8];
    {
        const int doff[8] = {-19,-18,-17,-1,1,17,18,19};
        #pragma unroll
        for (int k = 0; k < 8; k++) p36[k] = (pc + doff[k]) * NBSTRIDE;
    }

    float bel[10]; h2 beld[10];
    {
        const float2* bp = (const float2*)(beliefs + gpix*10);
        #pragma unroll
        for (int q = 0; q < 5; q++) {
            float2 v = bp[q];
            bel[2*q] = v.x; bel[2*q+1] = v.y;
            beld[2*q]   = pkrtz(v.x, v.x);
            beld[2*q+1] = pkrtz(v.y, v.y);
        }
    }
    h2 cond[24];
    {
        const float4* cp = (const float4*)(cons + gpix*24);
        #pragma unroll
        for (int r = 0; r < 6; r++) {
            float4 v = cp[r];
            cond[4*r+0] = pkrtz(v.x, v.x);
            cond[4*r+1] = pkrtz(v.y, v.y);
            cond[4*r+2] = pkrtz(v.z, v.z);
            cond[4*r+3] = pkrtz(v.w, v.w);
        }
    }

    float acc2[10];
    #pragma unroll
    for (int c = 0; c < 10; c++) acc2[c] = 0.f;

    // hp chunks of 4: one ds_read_b128 per (k, chunk)
    #pragma unroll 2
    for (int ch = 0; ch < 8; ch++) {
        const int hb = 4*ch;
        h2 t01[4], s01[4];
        #pragma unroll
        for (int j = 0; j < 4; j++) { t01[j] = Wfnb[b*32 + hb + j]; s01[j] = (h2)(_Float16)0; }
        #pragma unroll
        for (int c = 0; c < 10; c++) {
            #pragma unroll
            for (int j = 0; j < 4; j++)
                t01[j] = pkfma(beld[c], W[W_SELF + c*32 + hb + j], t01[j]);
        }
        h2 wc0[4], wc1[4], wc2[4];
        #pragma unroll
        for (int j = 0; j < 4; j++) {
            wc0[j] = W[W_WC      + hb + j];
            wc1[j] = W[W_WC + 32 + hb + j];
            wc2[j] = W[W_WC + 64 + hb + j];
        }
        #pragma unroll
        for (int k = 0; k < 8; k++) {
            const uint4 nv = *(const uint4*)(nbp_u + p36[k] + hb);
            const h2 nb[4] = { h2cast(nv.x), h2cast(nv.y), h2cast(nv.z), h2cast(nv.w) };
            const h2 c0 = cond[k*3+0], c1 = cond[k*3+1], c2 = cond[k*3+2];
            #pragma unroll
            for (int j = 0; j < 4; j++) {
                h2 v = t01[j] + nb[j];
                v = pkfma(c0, wc0[j], v);
                v = pkfma(c1, wc1[j], v);
                v = pkfma(c2, wc2[j], v);
                s01[j] += relu2(v);
            }
        }
        #pragma unroll
        for (int c = 0; c < 10; c++) {
            #pragma unroll
            for (int j = 0; j < 4; j++)
                acc2[c] = dot2f(s01[j], W[W_MW2 + c*32 + hb + j], acc2[c]);
        }
    }

    // agg = mean + mb2, duplicated-f16
    h2 aggd[10];
    #pragma unroll
    for (int c = 0; c < 10; c++) {
        float a = acc2[c]*0.125f + SC[c];
        aggd[c] = pkrtz(a, a);
    }

    float od[10];
    #pragma unroll
    for (int c = 0; c < 10; c++) od[c] = 0.f;

    #pragma unroll 4
    for (int hp = 0; hp < 32; hp++) {
        h2 u01 = W[W_UB1 + hp];
        #pragma unroll
        for (int c = 0; c < 10; c++) u01 = pkfma(beld[c], W[W_UW1 + c*32 + hp], u01);
        #pragma unroll
        for (int c = 0; c < 10; c++) u01 = pkfma(aggd[c], W[W_UW1 + (10+c)*32 + hp], u01);
        u01 = relu2(u01);
        #pragma unroll
        for (int c = 0; c < 10; c++) od[c] = dot2f(u01, W[W_UW2 + c*32 + hp], od[c]);
    }

    float x[10], mu = 0.f;
    #pragma unroll
    for (int c = 0; c < 10; c++) { x[c] = bel[c] + 0.5f*(od[c] + SC[10+c]); mu += x[c]; }
    mu *= 0.1f;
    float var = 0.f;
    #pragma unroll
    for (int c = 0; c < 10; c++) { float d = x[c] - mu; var += d*d; }
    var *= 0.1f;
    const float rs = rsqrtf(var + 1e-5f);

    float2* op = (float2*)(out + gpix*10);
    #pragma unroll
    for (int q = 0; q < 5; q++) {
        float2 r;
        r.x = (x[2*q]   - mu)*rs*SC[20+2*q]   + SC[30+2*q];
        r.y = (x[2*q+1] - mu)*rs*SC[20+2*q+1] + SC[30+2*q+1];
        op[q] = r;
    }
}

// ================== fallback (round-3 proven kernel, fp32 inputs) ==================
__device__ __forceinline__ float bf_lo(u32 v) { return __uint_as_float(v << 16); }
__device__ __forceinline__ float bf_hi(u32 v) { return __uint_as_float(v & 0xffff0000u); }
__device__ __forceinline__ u32 f2bf(float f) {
    u32 u = __float_as_uint(f);
    return (u + 0x7fffu + ((u >> 16) & 1u)) >> 16;
}
__device__ __forceinline__ u32 pack2(float a, float b) { return f2bf(a) | (f2bf(b) << 16); }
__device__ __forceinline__ u32 fpair(const float* a, int pi) { return pack2(a[2*pi], a[2*pi+1]); }

#define FW_MW2 736
#define FW_MB2 1056
#define FW_UW1 1061
#define FW_UB1 1701
#define FW_UW2 1733
#define FW_UB2 2053
#define FW_GAM 2058
#define FW_BET 2063
#define FW_TOT 2068

__global__ __launch_bounds__(256) void fallback_kernel(
    const float* __restrict__ beliefs, const float* __restrict__ cons, const float* __restrict__ fn,
    const float* __restrict__ mw1, const float* __restrict__ mb1, const float* __restrict__ mw2,
    const float* __restrict__ mb2, const float* __restrict__ uw1, const float* __restrict__ ub1,
    const float* __restrict__ uw2, const float* __restrict__ ub2, const float* __restrict__ gam,
    const float* __restrict__ bet, float* __restrict__ out)
{
    __shared__ float bel_s[NPIX*10];
    __shared__ u32   nbp_s[32*NPIX];
    __shared__ u32   w_s[FW_TOT];
    __shared__ float fnb_s[64];

    const int tid = threadIdx.x;
    const int b  = blockIdx.z;
    const int y0 = blockIdx.y * TILE;
    const int x0 = blockIdx.x * TILE;

    for (int i = tid; i < FW_TOT; i += 256) {
        u32 v;
        if      (i < 736)  v = fpair(mw1, i);
        else if (i < 1056) v = fpair(mw2, i - 736);
        else if (i < 1061) v = fpair(mb2, i - 1056);
        else if (i < 1701) v = fpair(uw1, i - 1061);
        else if (i < 1733) v = fpair(ub1, i - 1701);
        else if (i < 2053) v = fpair(uw2, i - 1733);
        else if (i < 2058) v = fpair(ub2, i - 2053);
        else if (i < 2063) v = fpair(gam, i - 2058);
        else               v = fpair(bet, i - 2063);
        w_s[i] = v;
    }
    if (tid < 64) {
        float acc = mb1[tid];
        #pragma unroll 8
        for (int f = 0; f < 32; f++)
            acc += fn[b*32 + f] * mw1[(23 + f)*64 + tid];
        fnb_s[tid] = acc;
    }
    for (int idx = tid; idx < NPIX*10; idx += 256) {
        int p = idx/10, c = idx - p*10;
        int py = p/HALO, px = p - py*HALO;
        int gy = y0-1+py; gy = gy<0?0:(gy>127?127:gy);
        int gx = x0-1+px; gx = gx<0?0:(gx>127?127:gx);
        bel_s[idx] = beliefs[((size_t)(b*128+gy)*128+gx)*10 + c];
    }
    __syncthreads();

    for (int p = tid; p < NPIX; p += 256) {
        float bl[10];
        #pragma unroll
        for (int c = 0; c < 10; c++) bl[c] = bel_s[p*10 + c];
        #pragma unroll 4
        for (int hp = 0; hp < 32; hp++) {
            float t0 = 0.f, t1 = 0.f;
            #pragma unroll
            for (int c = 0; c < 10; c++) {
                u32 wv = w_s[(10 + c)*32 + hp];
                t0 += bl[c] * bf_lo(wv);
                t1 += bl[c] * bf_hi(wv);
            }
            nbp_s[hp*NPIX + p] = pack2(t0, t1);
        }
    }
    __syncthreads();

    const int tx = tid & 15, ty = tid >> 4;
    const int pc = (ty + 1)*HALO + (tx + 1);
    float bel[10];
    #pragma unroll
    for (int c = 0; c < 10; c++) bel[c] = bel_s[pc*10 + c];
    const size_t gpix = (size_t)(b*128 + (y0 + ty))*128 + (x0 + tx);
    float con[24];
    #pragma unroll
    for (int j = 0; j < 24; j++) con[j] = cons[gpix*24 + j];

    float acc2[10];
    #pragma unroll
    for (int c = 0; c < 10; c++) acc2[c] = 0.f;

    #pragma unroll 2
    for (int hp = 0; hp < 32; hp++) {
        const int h0 = 2*hp, h1 = h0 + 1;
        float t0 = fnb_s[h0], t1 = fnb_s[h1];
        #pragma unroll
        for (int c = 0; c < 10; c++) {
            u32 wv = w_s[c*32 + hp];
            t0 += bel[c] * bf_lo(wv);
            t1 += bel[c] * bf_hi(wv);
        }
        const u32 wc0 = w_s[20*32 + hp], wc1 = w_s[21*32 + hp], wc2 = w_s[22*32 + hp];
        const u32* nbb = nbp_s + hp*NPIX + pc - 19;
        float s0 = 0.f, s1 = 0.f;
        #pragma unroll
        for (int k = 0; k < 8; k++) {
            const int doff[8] = { 0, 1, 2, 18, 20, 36, 37, 38 };
            u32 nv = nbb[doff[k]];
            float c0 = con[k*3], c1 = con[k*3+1], c2 = con[k*3+2];
            float v0 = t0 + bf_lo(nv) + c0*bf_lo(wc0) + c1*bf_lo(wc1) + c2*bf_lo(wc2);
            float v1 = t1 + bf_hi(nv) + c0*bf_hi(wc0) + c1*bf_hi(wc1) + c2*bf_hi(wc2);
            s0 += fmaxf(v0, 0.f);
            s1 += fmaxf(v1, 0.f);
        }
        #pragma unroll
        for (int cq = 0; cq < 5; cq++) {
            u32 a0 = w_s[FW_MW2 + h0*5 + cq];
            u32 a1 = w_s[FW_MW2 + h1*5 + cq];
            acc2[2*cq]   += s0*bf_lo(a0) + s1*bf_lo(a1);
            acc2[2*cq+1] += s0*bf_hi(a0) + s1*bf_hi(a1);
        }
    }

    float agg[10];
    #pragma unroll
    for (int cq = 0; cq < 5; cq++) {
        u32 bp = w_s[FW_MB2 + cq];
        agg[2*cq]   = acc2[2*cq]  *0.125f + bf_lo(bp);
        agg[2*cq+1] = acc2[2*cq+1]*0.125f + bf_hi(bp);
    }

    float od[10];
    #pragma unroll
    for (int c = 0; c < 10; c++) od[c] = 0.f;
    #pragma unroll 2
    for (int hp = 0; hp < 32; hp++) {
        u32 ubp = w_s[FW_UB1 + hp];
        float u0 = bf_lo(ubp), u1 = bf_hi(ubp);
        #pragma unroll
        for (int c = 0; c < 10; c++) {
            u32 wv = w_s[FW_UW1 + c*32 + hp];
            u0 += bel[c] * bf_lo(wv);
            u1 += bel[c] * bf_hi(wv);
        }
        #pragma unroll
        for (int c = 0; c < 10; c++) {
            u32 wv = w_s[FW_UW1 + (10 + c)*32 + hp];
            u0 += agg[c] * bf_lo(wv);
            u1 += agg[c] * bf_hi(wv);
        }
        u0 = fmaxf(u0, 0.f); u1 = fmaxf(u1, 0.f);
        const int h0 = 2*hp, h1 = h0 + 1;
        #pragma unroll
        for (int cq = 0; cq < 5; cq++) {
            u32 a0 = w_s[FW_UW2 + h0*5 + cq];
            u32 a1 = w_s[FW_UW2 + h1*5 + cq];
            od[2*cq]   += u0*bf_lo(a0) + u1*bf_lo(a1);
            od[2*cq+1] += u0*bf_hi(a0) + u1*bf_hi(a1);
        }
    }

    float x[10], mu = 0.f;
    #pragma unroll
    for (int cq = 0; cq < 5; cq++) {
        u32 bp = w_s[FW_UB2 + cq];
        x[2*cq]   = bel[2*cq]   + 0.5f*(od[2*cq]   + bf_lo(bp));
        x[2*cq+1] = bel[2*cq+1] + 0.5f*(od[2*cq+1] + bf_hi(bp));
        mu += x[2*cq] + x[2*cq+1];
    }
    mu *= 0.1f;
    float var = 0.f;
    #pragma unroll
    for (int c = 0; c < 10; c++) { float d = x[c] - mu; var += d*d; }
    var *= 0.1f;
    const float rs = rsqrtf(var + 1e-5f);

    float2* op = reinterpret_cast<float2*>(out + gpix*10);
    #pragma unroll
    for (int q = 0; q < 5; q++) {
        u32 gp = w_s[FW_GAM + q], bq = w_s[FW_BET + q];
        float2 r;
        r.x = (x[2*q]   - mu)*rs*bf_lo(gp) + bf_lo(bq);
        r.y = (x[2*q+1] - mu)*rs*bf_hi(gp) + bf_hi(bq);
        op[q] = r;
    }
}

extern "C" void kernel_launch(void* const* d_in, const int* in_sizes, int n_in,
                              void* d_out, int out_size, void* d_ws, size_t ws_size,
                              hipStream_t stream) {
    (void)in_sizes; (void)n_in; (void)out_size;
    const float* beliefs = (const float*)d_in[0];
    const float* cons    = (const float*)d_in[1];
    const float* fn      = (const float*)d_in[2];
    const float* mw1     = (const float*)d_in[3];
    const float* mb1     = (const float*)d_in[4];
    const float* mw2     = (const float*)d_in[5];
    const float* mb2     = (const float*)d_in[6];
    const float* uw1     = (const float*)d_in[7];
    const float* ub1     = (const float*)d_in[8];
    const float* uw2     = (const float*)d_in[9];
    const float* ub2     = (const float*)d_in[10];
    const float* gam     = (const float*)d_in[11];
    const float* bet     = (const float*)d_in[12];
    float* outp = (float*)d_out;

    if (ws_size >= (size_t)WS_DWORDS*4) {
        prep_kernel<<<dim3(64), dim3(64), 0, stream>>>(
            fn, mw1, mb1, mw2, mb2, uw1, ub1, uw2, ub2, gam, bet, (u32*)d_ws);
        mp_kernel<<<dim3(8, 8, 64), dim3(256), 0, stream>>>(
            beliefs, cons, (const u32*)d_ws, outp);
    } else {
        fallback_kernel<<<dim3(8, 8, 64), dim3(256), 0, stream>>>(
            beliefs, cons, fn, mw1, mb1, mw2, mb2, uw1, ub1, uw2, ub2, gam, bet, outp);
    }
}